// Round 1
// 16718.698 us; speedup vs baseline: 1.4563x; 1.4563x over previous
//
#include <hip/hip_runtime.h>

typedef unsigned short u16;
typedef __attribute__((ext_vector_type(8))) __bf16 bf16x8;
typedef __attribute__((ext_vector_type(4))) float f32x4;

// Problem constants
#define NWG 256
#define CHUNK 64          // timesteps per chunk (Xp chunk = 32 MiB bf16)
#define NCHUNK 16

__device__ __forceinline__ u16 f2b(float f) {
  union { float f; unsigned u; } v; v.f = f;
  unsigned r = (v.u + 0x7fffu + ((v.u >> 16) & 1u)) >> 16;
  return (u16)r;
}
__device__ __forceinline__ float b2f(u16 u) {
  union { unsigned u; float f; } v; v.u = ((unsigned)u) << 16;
  return v.f;
}
__device__ __forceinline__ float sig(float x) { return 1.0f / (1.0f + __expf(-x)); }
__device__ __forceinline__ float tanh_(float x) { return 2.0f / (1.0f + __expf(-2.0f * x)) - 1.0f; }

// ---------------------------------------------------------------------------
// prep: Wc[4096][2048] bf16 = [W_ih | W_hh]; bias = b_ih + b_hh (fp32);
//       hbuf parity-0 = bf16(h0); cst = c0 (fp32)
// ---------------------------------------------------------------------------
__global__ __launch_bounds__(256) void prep_kernel(
    const float* __restrict__ W_ih, const float* __restrict__ W_hh,
    const float* __restrict__ b_ih, const float* __restrict__ b_hh,
    const float* __restrict__ h0, const float* __restrict__ c0,
    u16* __restrict__ Wc, float* __restrict__ bias,
    u16* __restrict__ hbuf, float* __restrict__ cst)
{
  const int tid = threadIdx.x;
  const int blk = blockIdx.x;
  // weight row blk
  {
    const float4 a = *reinterpret_cast<const float4*>(W_ih + (size_t)blk * 1024 + tid * 4);
    const float4 b = *reinterpret_cast<const float4*>(W_hh + (size_t)blk * 1024 + tid * 4);
    u16* dst = Wc + (size_t)blk * 2048;
    *reinterpret_cast<ushort4*>(dst + tid * 4) =
        make_ushort4(f2b(a.x), f2b(a.y), f2b(a.z), f2b(a.w));
    *reinterpret_cast<ushort4*>(dst + 1024 + tid * 4) =
        make_ushort4(f2b(b.x), f2b(b.y), f2b(b.z), f2b(b.w));
  }
  if (blk < 16) {
    int i = blk * 256 + tid;
    bias[i] = b_ih[i] + b_hh[i];
  } else if (blk < 80) {
    int row = blk - 16, k = tid * 4;
    float4 v = *reinterpret_cast<const float4*>(h0 + (size_t)row * 1024 + k);
    *reinterpret_cast<ushort4*>(hbuf + (size_t)row * 1024 + k) =
        make_ushort4(f2b(v.x), f2b(v.y), f2b(v.z), f2b(v.w));
  } else if (blk < 144) {
    int row = blk - 80, k = tid * 4;
    *reinterpret_cast<float4*>(cst + (size_t)row * 1024 + k) =
        *reinterpret_cast<const float4*>(c0 + (size_t)row * 1024 + k);
  }
}

// ---------------------------------------------------------------------------
// xproj: Xp[m][n] = sum_k x_chunk[m][k] * Wc[n][k]   (m = (t-t0)*64+b, chunk M=4096)
// 128x128 tile, 4 waves 2x2, K staged in 64-chunks, bf16 MFMA 16x16x32.
// ---------------------------------------------------------------------------
__global__ __launch_bounds__(256) void xproj_kernel(
    const float* __restrict__ xc, const u16* __restrict__ Wc, u16* __restrict__ Xp)
{
  __shared__ __align__(16) u16 As[128][72];   // pitch 72 -> 2-way (free) bank aliasing
  __shared__ __align__(16) u16 Bs[128][72];
  const int tid = threadIdx.x;
  const int w = tid >> 6, l = tid & 63;
  const int bm = blockIdx.x & 31;        // 32 m-tiles (M=4096)
  const int bn = blockIdx.x >> 5;        // 32 n-tiles (N=4096)
  const int m0 = bm << 7, n0 = bn << 7;
  const int wm = w & 1, wn = w >> 1;
  const int lr = l & 15, lq = l >> 4;

  f32x4 acc[4][4];
  for (int i = 0; i < 4; ++i)
    for (int j = 0; j < 4; ++j) acc[i][j] = (f32x4){0.f, 0.f, 0.f, 0.f};

  for (int kc = 0; kc < 1024; kc += 64) {
    {  // stage A (fp32 -> bf16): 128 rows x 64 k
      const int k4 = (tid & 15) << 2;
      const int rb = tid >> 4;
      for (int rp = 0; rp < 128; rp += 16) {
        int row = rp + rb;
        float4 v = *reinterpret_cast<const float4*>(xc + (size_t)(m0 + row) * 1024 + kc + k4);
        unsigned lo = (unsigned)f2b(v.x) | ((unsigned)f2b(v.y) << 16);
        unsigned hi = (unsigned)f2b(v.z) | ((unsigned)f2b(v.w) << 16);
        *reinterpret_cast<uint2*>(&As[row][k4]) = make_uint2(lo, hi);
      }
    }
    {  // stage B (already bf16): 128 rows x 64 k
      const int kk = (tid & 7) << 3;
      const int rb = tid >> 3;
      for (int rp = 0; rp < 128; rp += 32) {
        int row = rp + rb;
        uint4 v = *reinterpret_cast<const uint4*>(Wc + (size_t)(n0 + row) * 2048 + kc + kk);
        *reinterpret_cast<uint4*>(&Bs[row][kk]) = v;
      }
    }
    __syncthreads();
    for (int kb = 0; kb < 2; ++kb) {
      const int ko = kb * 32 + lq * 8;
      bf16x8 af[4], bfr[4];
      for (int i = 0; i < 4; ++i)
        af[i] = *reinterpret_cast<const bf16x8*>(&As[(wm << 6) + (i << 4) + lr][ko]);
      for (int j = 0; j < 4; ++j)
        bfr[j] = *reinterpret_cast<const bf16x8*>(&Bs[(wn << 6) + (j << 4) + lr][ko]);
      for (int i = 0; i < 4; ++i)
        for (int j = 0; j < 4; ++j)
          acc[i][j] = __builtin_amdgcn_mfma_f32_16x16x32_bf16(af[i], bfr[j], acc[i][j], 0, 0, 0);
    }
    __syncthreads();
  }
  // epilogue: D row = (lane>>4)*4 + reg, col = lane&15  [guide-verified]
  for (int i = 0; i < 4; ++i)
    for (int j = 0; j < 4; ++j) {
      int row0 = m0 + (wm << 6) + (i << 4) + lq * 4;
      int coln = n0 + (wn << 6) + (j << 4) + lr;
      for (int r = 0; r < 4; ++r)
        Xp[(size_t)(row0 + r) * 4096 + coln] = f2b(acc[i][j][r]);
    }
}

// ---------------------------------------------------------------------------
// scan: persistent, 256 WGs. WG g owns h-cols [4g,4g+4) -> 16 gate cols.
// W_hh slice lives in LDS (fragment order). One grid barrier per step.
//
// Barrier redesign (this round): distributed arrive/release flags.
//  - worker g: one release fence + relaxed store to its OWN padded flag
//  - WG0: 255 threads poll the 255 flags in parallel with RELAXED loads
//    (no per-poll cache invalidation), one acquire fence when done
//  - release broadcast through 64 padded copies, workers poll relaxed,
//    one acquire fence on exit
//  - out-stores + next-step Xp prefetch issued inside the barrier window
//    (after arrive, overlapping the spin) instead of before it
//  - last step of each chunk skips the barrier (kernel boundary syncs)
// ---------------------------------------------------------------------------
__global__ __launch_bounds__(256) void scan_kernel(
    const u16* __restrict__ Wc, const u16* __restrict__ Xp,
    u16* __restrict__ hbuf, float* __restrict__ cst, const float* __restrict__ bias,
    float* __restrict__ out, float* __restrict__ outT, float* __restrict__ cT,
    unsigned* __restrict__ arv, unsigned* __restrict__ rel, int t0, int C)
{
  __shared__ __align__(16) u16 Wlds[32 * 64 * 8];  // [kb][lane][8] fragment order, 32 KB
  const int tid = threadIdx.x;
  const int g = blockIdx.x;
  const int w = tid >> 6, l = tid & 63;
  const int n = l & 15, kq = l >> 4;
  const int jj = (g << 2) + (n & 3);              // h-column for this lane (if n<4: n&3==n)
  const int col = ((n >> 2) << 10) + jj;          // gate column: gate = n>>2 (i,f,g,o)

  // load W_hh slice into LDS in B-fragment order: B[k][n] = Wc[col(n)][1024+k]
  for (int i = tid; i < 2048; i += 256) {
    int kb = i >> 6, l2 = i & 63;
    int nn = l2 & 15, kq2 = l2 >> 4;
    int c2 = ((nn >> 2) << 10) + (g << 2) + (nn & 3);
    uint4 v = *reinterpret_cast<const uint4*>(Wc + (size_t)c2 * 2048 + 1024 + kb * 32 + kq2 * 8);
    *reinterpret_cast<uint4*>(&Wlds[i * 8]) = v;
  }
  const float biasv = bias[col];
  const int brow = (w << 4) + (kq << 2);          // batch row base for D regs
  float creg[4];
  if (n < 4)
    for (int r = 0; r < 4; ++r) creg[r] = cst[(size_t)(brow + r) * 1024 + jj];
  __syncthreads();

  // prefetch Xp gate preacts for ts=0
  float xv[4];
  {
    const u16* xpr = Xp + ((size_t)brow << 12) + col;
    for (int r = 0; r < 4; ++r) xv[r] = b2f(xpr[(size_t)r << 12]);
  }

  for (int ts = 0; ts < C; ++ts) {
    const int t = t0 + ts;
    const u16* hs = hbuf + ((t & 1) ? 65536 : 0);
    u16* hd = hbuf + ((t & 1) ? 0 : 65536);
    // A-fragment directly from global h: A[m=lane&15][k=(lane>>4)*8+j]
    const u16* arow = hs + (size_t)((w << 4) + n) * 1024 + (kq << 3);
    f32x4 acc0 = {0.f, 0.f, 0.f, 0.f};
    f32x4 acc1 = {0.f, 0.f, 0.f, 0.f};
#pragma unroll
    for (int kb = 0; kb < 32; kb += 2) {
      bf16x8 a0 = *reinterpret_cast<const bf16x8*>(arow + (kb << 5));
      bf16x8 w0 = *reinterpret_cast<const bf16x8*>(&Wlds[((kb << 6) + l) << 3]);
      acc0 = __builtin_amdgcn_mfma_f32_16x16x32_bf16(a0, w0, acc0, 0, 0, 0);
      bf16x8 a1 = *reinterpret_cast<const bf16x8*>(arow + ((kb + 1) << 5));
      bf16x8 w1 = *reinterpret_cast<const bf16x8*>(&Wlds[(((kb + 1) << 6) + l) << 3]);
      acc1 = __builtin_amdgcn_mfma_f32_16x16x32_bf16(a1, w1, acc1, 0, 0, 0);
    }
    // gate preacts for all lanes (lanes n>=4 are shuffle sources)
    float gv[4];
    for (int r = 0; r < 4; ++r) gv[r] = acc0[r] + acc1[r] + xv[r] + biasv;
    const int sb = (l & 48) | (n & 3);
    float fp[4], gp[4], op[4];
    for (int r = 0; r < 4; ++r) {
      fp[r] = __shfl(gv[r], sb + 4);
      gp[r] = __shfl(gv[r], sb + 8);
      op[r] = __shfl(gv[r], sb + 12);
    }
    float hv[4];
    if (n < 4) {
      for (int r = 0; r < 4; ++r) {
        float iv = sig(gv[r]);
        float fv = sig(fp[r]);
        float gg = tanh_(gp[r]);
        float ov = sig(op[r]);
        float cn = fv * creg[r] + iv * gg;
        hv[r] = ov * tanh_(cn);
        creg[r] = cn;
        // h for next step: must be visible before arrive is published
        hd[(size_t)(brow + r) * 1024 + jj] = f2b(hv[r]);
      }
    }

    if (ts + 1 < C) {
      const unsigned v = (unsigned)(t + 1);
      __syncthreads();  // drains hd stores of all threads to L2
      if (g == 0) {
        // overlap with polling: out stores + next-step Xp prefetch
        if (n < 4)
          for (int r = 0; r < 4; ++r)
            out[((size_t)t * 64 + (brow + r)) * 1024 + jj] = hv[r];
        {
          const u16* xpr = Xp + ((size_t)((ts + 1) * 64 + brow) << 12) + col;
          for (int r = 0; r < 4; ++r) xv[r] = b2f(xpr[(size_t)r << 12]);
        }
        if (tid > 0)
          while (__hip_atomic_load(&arv[tid << 5], __ATOMIC_RELAXED, __HIP_MEMORY_SCOPE_AGENT) < v)
            __builtin_amdgcn_s_sleep(1);
        __builtin_amdgcn_fence(__ATOMIC_ACQUIRE, "agent");
        __syncthreads();
        if (tid < 64) {
          __builtin_amdgcn_fence(__ATOMIC_RELEASE, "agent");
          __hip_atomic_store(&rel[tid << 5], v, __ATOMIC_RELAXED, __HIP_MEMORY_SCOPE_AGENT);
        }
      } else {
        if (tid == 0) {
          __builtin_amdgcn_fence(__ATOMIC_RELEASE, "agent");  // wbl2 covers WG's hd stores
          __hip_atomic_store(&arv[g << 5], v, __ATOMIC_RELAXED, __HIP_MEMORY_SCOPE_AGENT);
        }
        // overlap with spin: out stores + next-step Xp prefetch
        if (n < 4)
          for (int r = 0; r < 4; ++r)
            out[((size_t)t * 64 + (brow + r)) * 1024 + jj] = hv[r];
        {
          const u16* xpr = Xp + ((size_t)((ts + 1) * 64 + brow) << 12) + col;
          for (int r = 0; r < 4; ++r) xv[r] = b2f(xpr[(size_t)r << 12]);
        }
        if (tid == 0) {
          while (__hip_atomic_load(&rel[(g & 63) << 5], __ATOMIC_RELAXED, __HIP_MEMORY_SCOPE_AGENT) < v)
            __builtin_amdgcn_s_sleep(1);
          __builtin_amdgcn_fence(__ATOMIC_ACQUIRE, "agent");
        }
        __syncthreads();
      }
    } else {
      // last step of chunk: kernel boundary provides the sync
      if (n < 4)
        for (int r = 0; r < 4; ++r)
          out[((size_t)t * 64 + (brow + r)) * 1024 + jj] = hv[r];
    }
    if (t == 1023 && n < 4)
      for (int r = 0; r < 4; ++r) outT[(size_t)(brow + r) * 1024 + jj] = hv[r];
  }
  if (n < 4) {
    for (int r = 0; r < 4; ++r) cst[(size_t)(brow + r) * 1024 + jj] = creg[r];
    if (t0 + C == 1024)
      for (int r = 0; r < 4; ++r) cT[(size_t)(brow + r) * 1024 + jj] = creg[r];
  }
}

// ---------------------------------------------------------------------------
extern "C" void kernel_launch(void* const* d_in, const int* in_sizes, int n_in,
                              void* d_out, int out_size, void* d_ws, size_t ws_size,
                              hipStream_t stream)
{
  const float* x    = (const float*)d_in[0];
  const float* W_ih = (const float*)d_in[1];
  const float* W_hh = (const float*)d_in[2];
  const float* b_ih = (const float*)d_in[3];
  const float* b_hh = (const float*)d_in[4];
  const float* h0   = (const float*)d_in[5];
  const float* c0   = (const float*)d_in[6];
  float* out  = (float*)d_out;
  float* outT = out + (size_t)1024 * 64 * 1024;   // h_T
  float* cT   = outT + 64 * 1024;                 // c_T

  unsigned char* ws = (unsigned char*)d_ws;
  size_t off = 0;
  u16* Wc = (u16*)(ws + off);      off += (size_t)4096 * 2048 * 2;  // 16 MiB
  float* bias = (float*)(ws + off); off += 4096 * 4;
  u16* hbuf = (u16*)(ws + off);    off += (size_t)2 * 65536 * 2;    // ping-pong h (bf16)
  float* cst = (float*)(ws + off); off += (size_t)65536 * 4;        // c state
  unsigned* arv = (unsigned*)(ws + off); off += 256 * 32 * 4;       // arrive flags, 128B padded
  unsigned* rel = (unsigned*)(ws + off); off += 64 * 32 * 4;        // release copies, 128B padded
  u16* Xp = (u16*)(ws + off);      // 32 MiB chunk buffer; total ws need ~48.6 MiB

  hipMemsetAsync(arv, 0, (256 * 32 + 64 * 32) * 4, stream);  // arv+rel contiguous
  hipLaunchKernelGGL(prep_kernel, dim3(4096), dim3(256), 0, stream,
                     W_ih, W_hh, b_ih, b_hh, h0, c0, Wc, bias, hbuf, cst);

  for (int c = 0; c < NCHUNK; ++c) {
    int t0 = c * CHUNK;
    hipLaunchKernelGGL(xproj_kernel, dim3(1024), dim3(256), 0, stream,
                       x + (size_t)t0 * 65536, Wc, Xp);
    int C = CHUNK;
    void* args[] = {&Wc, &Xp, &hbuf, &cst, &bias, &out, &outT, &cT, &arv, &rel, &t0, &C};
    if (hipLaunchCooperativeKernel(reinterpret_cast<void*>(scan_kernel),
                                   dim3(NWG), dim3(256), args, 0, stream) != hipSuccess) {
      (void)hipGetLastError();
      hipLaunchKernelGGL(scan_kernel, dim3(NWG), dim3(256), 0, stream,
                         Wc, Xp, hbuf, cst, bias, out, outT, cT, arv, rel, t0, CHUNK);
    }
  }
}

// Round 3
// 16365.863 us; speedup vs baseline: 1.4877x; 1.0216x over previous
//
#include <hip/hip_runtime.h>

typedef unsigned short u16;
typedef __attribute__((ext_vector_type(8))) __bf16 bf16x8;
typedef __attribute__((ext_vector_type(4))) float f32x4;

// Problem constants
#define NWG 256
#define CHUNK 64          // timesteps per chunk (Xp chunk = 32 MiB bf16)
#define NCHUNK 16

__device__ __forceinline__ u16 f2b(float f) {
  union { float f; unsigned u; } v; v.f = f;
  unsigned r = (v.u + 0x7fffu + ((v.u >> 16) & 1u)) >> 16;
  return (u16)r;
}
__device__ __forceinline__ float b2f(u16 u) {
  union { unsigned u; float f; } v; v.u = ((unsigned)u) << 16;
  return v.f;
}
__device__ __forceinline__ float sig(float x) { return 1.0f / (1.0f + __expf(-x)); }
__device__ __forceinline__ float tanh_(float x) { return 2.0f / (1.0f + __expf(-2.0f * x)) - 1.0f; }

// ---------------------------------------------------------------------------
// prep: Wc[4096][2048] bf16 = [W_ih | W_hh]; bias = b_ih + b_hh (fp32);
//       hbuf parity-0 = bf16(h0); cst = c0 (fp32)
// ---------------------------------------------------------------------------
__global__ __launch_bounds__(256) void prep_kernel(
    const float* __restrict__ W_ih, const float* __restrict__ W_hh,
    const float* __restrict__ b_ih, const float* __restrict__ b_hh,
    const float* __restrict__ h0, const float* __restrict__ c0,
    u16* __restrict__ Wc, float* __restrict__ bias,
    u16* __restrict__ hbuf, float* __restrict__ cst)
{
  const int tid = threadIdx.x;
  const int blk = blockIdx.x;
  // weight row blk
  {
    const float4 a = *reinterpret_cast<const float4*>(W_ih + (size_t)blk * 1024 + tid * 4);
    const float4 b = *reinterpret_cast<const float4*>(W_hh + (size_t)blk * 1024 + tid * 4);
    u16* dst = Wc + (size_t)blk * 2048;
    *reinterpret_cast<ushort4*>(dst + tid * 4) =
        make_ushort4(f2b(a.x), f2b(a.y), f2b(a.z), f2b(a.w));
    *reinterpret_cast<ushort4*>(dst + 1024 + tid * 4) =
        make_ushort4(f2b(b.x), f2b(b.y), f2b(b.z), f2b(b.w));
  }
  if (blk < 16) {
    int i = blk * 256 + tid;
    bias[i] = b_ih[i] + b_hh[i];
  } else if (blk < 80) {
    int row = blk - 16, k = tid * 4;
    float4 v = *reinterpret_cast<const float4*>(h0 + (size_t)row * 1024 + k);
    *reinterpret_cast<ushort4*>(hbuf + (size_t)row * 1024 + k) =
        make_ushort4(f2b(v.x), f2b(v.y), f2b(v.z), f2b(v.w));
  } else if (blk < 144) {
    int row = blk - 80, k = tid * 4;
    *reinterpret_cast<float4*>(cst + (size_t)row * 1024 + k) =
        *reinterpret_cast<const float4*>(c0 + (size_t)row * 1024 + k);
  }
}

// ---------------------------------------------------------------------------
// xproj: Xp[m][n] = sum_k x_chunk[m][k] * Wc[n][k]   (m = (t-t0)*64+b, chunk M=4096)
// 128x128 tile, 4 waves 2x2, K staged in 64-chunks, bf16 MFMA 16x16x32.
// ---------------------------------------------------------------------------
__global__ __launch_bounds__(256) void xproj_kernel(
    const float* __restrict__ xc, const u16* __restrict__ Wc, u16* __restrict__ Xp)
{
  __shared__ __align__(16) u16 As[128][72];   // pitch 72 -> 2-way (free) bank aliasing
  __shared__ __align__(16) u16 Bs[128][72];
  const int tid = threadIdx.x;
  const int w = tid >> 6, l = tid & 63;
  const int bm = blockIdx.x & 31;        // 32 m-tiles (M=4096)
  const int bn = blockIdx.x >> 5;        // 32 n-tiles (N=4096)
  const int m0 = bm << 7, n0 = bn << 7;
  const int wm = w & 1, wn = w >> 1;
  const int lr = l & 15, lq = l >> 4;

  f32x4 acc[4][4];
  for (int i = 0; i < 4; ++i)
    for (int j = 0; j < 4; ++j) acc[i][j] = (f32x4){0.f, 0.f, 0.f, 0.f};

  for (int kc = 0; kc < 1024; kc += 64) {
    {  // stage A (fp32 -> bf16): 128 rows x 64 k
      const int k4 = (tid & 15) << 2;
      const int rb = tid >> 4;
      for (int rp = 0; rp < 128; rp += 16) {
        int row = rp + rb;
        float4 v = *reinterpret_cast<const float4*>(xc + (size_t)(m0 + row) * 1024 + kc + k4);
        unsigned lo = (unsigned)f2b(v.x) | ((unsigned)f2b(v.y) << 16);
        unsigned hi = (unsigned)f2b(v.z) | ((unsigned)f2b(v.w) << 16);
        *reinterpret_cast<uint2*>(&As[row][k4]) = make_uint2(lo, hi);
      }
    }
    {  // stage B (already bf16): 128 rows x 64 k
      const int kk = (tid & 7) << 3;
      const int rb = tid >> 3;
      for (int rp = 0; rp < 128; rp += 32) {
        int row = rp + rb;
        uint4 v = *reinterpret_cast<const uint4*>(Wc + (size_t)(n0 + row) * 2048 + kc + kk);
        *reinterpret_cast<uint4*>(&Bs[row][kk]) = v;
      }
    }
    __syncthreads();
    for (int kb = 0; kb < 2; ++kb) {
      const int ko = kb * 32 + lq * 8;
      bf16x8 af[4], bfr[4];
      for (int i = 0; i < 4; ++i)
        af[i] = *reinterpret_cast<const bf16x8*>(&As[(wm << 6) + (i << 4) + lr][ko]);
      for (int j = 0; j < 4; ++j)
        bfr[j] = *reinterpret_cast<const bf16x8*>(&Bs[(wn << 6) + (j << 4) + lr][ko]);
      for (int i = 0; i < 4; ++i)
        for (int j = 0; j < 4; ++j)
          acc[i][j] = __builtin_amdgcn_mfma_f32_16x16x32_bf16(af[i], bfr[j], acc[i][j], 0, 0, 0);
    }
    __syncthreads();
  }
  // epilogue: D row = (lane>>4)*4 + reg, col = lane&15  [guide-verified]
  for (int i = 0; i < 4; ++i)
    for (int j = 0; j < 4; ++j) {
      int row0 = m0 + (wm << 6) + (i << 4) + lq * 4;
      int coln = n0 + (wn << 6) + (j << 4) + lr;
      for (int r = 0; r < 4; ++r)
        Xp[(size_t)(row0 + r) * 4096 + coln] = f2b(acc[i][j][r]);
    }
}

// ---------------------------------------------------------------------------
// scan: persistent, 256 WGs. WG g owns h-cols [4g,4g+4) -> 16 gate cols.
// W_hh slice lives in LDS (fragment order). One grid barrier per step.
//
// Round-3: round-2 structure with the lane-transpose bug FIXED.
//  - transpose gather base is (l & 48), NOT sb=(l&48)|n. st elem m =
//    (shfl(pw,(l&48)+m) >> (n*16)) & 0xffff = h[brow+n][4g+m]; all source
//    lanes m=0..3 are active under if(n<4).
//  - ONE-HOP all-to-all barrier: each WG posts its own padded flag; thread
//    tid polls WG tid's flag (relaxed agent loads), one acquire fence.
//  - hd/out stores write-through (agent-scope relaxed atomic -> sc1, complete
//    at coherence point); per-wave vmcnt drain at __syncthreads is the
//    release; acquire fence (L1/L2 inv) after the barrier, before h loads.
//  - Deep A prefetch: all 32 h fragments in registers before the MFMA chain.
// ---------------------------------------------------------------------------
__global__ __launch_bounds__(256, 1) void scan_kernel(
    const u16* __restrict__ Wc, const u16* __restrict__ Xp,
    u16* __restrict__ hbuf, float* __restrict__ cst, const float* __restrict__ bias,
    float* __restrict__ out, float* __restrict__ outT, float* __restrict__ cT,
    unsigned* __restrict__ arv, int t0, int C)
{
  __shared__ __align__(16) u16 Wlds[32 * 64 * 8];  // [kb][lane][8] fragment order, 32 KB
  const int tid = threadIdx.x;
  const int g = blockIdx.x;
  const int w = tid >> 6, l = tid & 63;
  const int n = l & 15, kq = l >> 4;
  const int jj = (g << 2) + (n & 3);              // h-column for this lane (if n<4: n&3==n)
  const int col = ((n >> 2) << 10) + jj;          // gate column: gate = n>>2 (i,f,g,o)

  // load W_hh slice into LDS in B-fragment order: B[k][n] = Wc[col(n)][1024+k]
  for (int i = tid; i < 2048; i += 256) {
    int kb = i >> 6, l2 = i & 63;
    int nn = l2 & 15, kq2 = l2 >> 4;
    int c2 = ((nn >> 2) << 10) + (g << 2) + (nn & 3);
    uint4 v = *reinterpret_cast<const uint4*>(Wc + (size_t)c2 * 2048 + 1024 + kb * 32 + kq2 * 8);
    *reinterpret_cast<uint4*>(&Wlds[i * 8]) = v;
  }
  const float biasv = bias[col];
  const int brow = (w << 4) + (kq << 2);          // batch row base for D regs
  float creg[4];
  if (n < 4)
    for (int r = 0; r < 4; ++r) creg[r] = cst[(size_t)(brow + r) * 1024 + jj];
  __syncthreads();

  // prefetch Xp gate preacts for ts=0
  float xv[4];
  {
    const u16* xpr = Xp + ((size_t)brow << 12) + col;
    for (int r = 0; r < 4; ++r) xv[r] = b2f(xpr[(size_t)r << 12]);
  }

  for (int ts = 0; ts < C; ++ts) {
    const int t = t0 + ts;
    const u16* hs = hbuf + ((t & 1) ? 65536 : 0);
    u16* hd = hbuf + ((t & 1) ? 0 : 65536);
    // A-fragment directly from global h: A[m=lane&15][k=(lane>>4)*8+j]
    // Deep prefetch: issue ALL 32 fragment loads, then run the MFMA chain.
    const u16* arow = hs + (size_t)((w << 4) + n) * 1024 + (kq << 3);
    bf16x8 af[32];
#pragma unroll
    for (int kb = 0; kb < 32; ++kb)
      af[kb] = *reinterpret_cast<const bf16x8*>(arow + (kb << 5));
    f32x4 ac0 = {0.f, 0.f, 0.f, 0.f};
    f32x4 ac1 = {0.f, 0.f, 0.f, 0.f};
    f32x4 ac2 = {0.f, 0.f, 0.f, 0.f};
    f32x4 ac3 = {0.f, 0.f, 0.f, 0.f};
#pragma unroll
    for (int kb = 0; kb < 32; kb += 4) {
      ac0 = __builtin_amdgcn_mfma_f32_16x16x32_bf16(
          af[kb + 0], *reinterpret_cast<const bf16x8*>(&Wlds[(((kb + 0) << 6) + l) << 3]), ac0, 0, 0, 0);
      ac1 = __builtin_amdgcn_mfma_f32_16x16x32_bf16(
          af[kb + 1], *reinterpret_cast<const bf16x8*>(&Wlds[(((kb + 1) << 6) + l) << 3]), ac1, 0, 0, 0);
      ac2 = __builtin_amdgcn_mfma_f32_16x16x32_bf16(
          af[kb + 2], *reinterpret_cast<const bf16x8*>(&Wlds[(((kb + 2) << 6) + l) << 3]), ac2, 0, 0, 0);
      ac3 = __builtin_amdgcn_mfma_f32_16x16x32_bf16(
          af[kb + 3], *reinterpret_cast<const bf16x8*>(&Wlds[(((kb + 3) << 6) + l) << 3]), ac3, 0, 0, 0);
    }
    // gate preacts for all lanes (lanes n>=4 are shuffle sources)
    float gv[4];
    for (int r = 0; r < 4; ++r)
      gv[r] = ((ac0[r] + ac1[r]) + (ac2[r] + ac3[r])) + xv[r] + biasv;
    const int sb = (l & 48) | (n & 3);
    float fp[4], gp[4], op[4];
    for (int r = 0; r < 4; ++r) {
      fp[r] = __shfl(gv[r], sb + 4);
      gp[r] = __shfl(gv[r], sb + 8);
      op[r] = __shfl(gv[r], sb + 12);
    }
    float hv[4];
    if (n < 4) {
      for (int r = 0; r < 4; ++r) {
        float iv = sig(gv[r]);
        float fv = sig(fp[r]);
        float gg = tanh_(gp[r]);
        float ov = sig(op[r]);
        float cn = fv * creg[r] + iv * gg;
        hv[r] = ov * tanh_(cn);
        creg[r] = cn;
      }
      // 4x4 u16 lane transpose -> one aligned 8B write-through store per lane.
      // pw elem r = h[brow+r][4g+n]. Gather base is (l&48): q_m = pw of lane
      // (kq*16+m); st elem m = (q_m >> (n*16)) = h[brow+n][4g+m].
      unsigned long long pw = (unsigned long long)f2b(hv[0])
                            | ((unsigned long long)f2b(hv[1]) << 16)
                            | ((unsigned long long)f2b(hv[2]) << 32)
                            | ((unsigned long long)f2b(hv[3]) << 48);
      const int tb = l & 48;
      unsigned long long q0 = __shfl(pw, tb + 0);
      unsigned long long q1 = __shfl(pw, tb + 1);
      unsigned long long q2 = __shfl(pw, tb + 2);
      unsigned long long q3 = __shfl(pw, tb + 3);
      const int sh = n << 4;
      unsigned long long st = ((q0 >> sh) & 0xffffull)
                            | (((q1 >> sh) & 0xffffull) << 16)
                            | (((q2 >> sh) & 0xffffull) << 32)
                            | (((q3 >> sh) & 0xffffull) << 48);
      __hip_atomic_store(
          reinterpret_cast<unsigned long long*>(hd + (size_t)(brow + n) * 1024 + (g << 2)),
          st, __ATOMIC_RELAXED, __HIP_MEMORY_SCOPE_AGENT);
    }

    if (ts + 1 < C) {
      const unsigned v = (unsigned)(t + 1);
      __syncthreads();  // each wave drains vmcnt -> all hd stores acked at L3
      if (tid == 0) {
        asm volatile("s_waitcnt vmcnt(0)" ::: "memory");
        __hip_atomic_store(&arv[g << 5], v, __ATOMIC_RELAXED, __HIP_MEMORY_SCOPE_AGENT);
      }
      // overlap with polling: out stores (write-through, unordered vs flag)
      // + next-step Xp prefetch
      if (n < 4)
        for (int r = 0; r < 4; ++r)
          __hip_atomic_store(&out[((size_t)t * 64 + (brow + r)) * 1024 + jj], hv[r],
                             __ATOMIC_RELAXED, __HIP_MEMORY_SCOPE_AGENT);
      {
        const u16* xpr = Xp + ((size_t)((ts + 1) * 64 + brow) << 12) + col;
        for (int r = 0; r < 4; ++r) xv[r] = b2f(xpr[(size_t)r << 12]);
      }
      // one-hop all-to-all: thread tid polls WG tid's flag
      while (__hip_atomic_load(&arv[tid << 5], __ATOMIC_RELAXED, __HIP_MEMORY_SCOPE_AGENT) < v)
        __builtin_amdgcn_s_sleep(1);
      __syncthreads();
      __builtin_amdgcn_fence(__ATOMIC_ACQUIRE, "agent");  // inv L1/L2 before h loads
    } else {
      // last step of chunk: kernel boundary provides the sync
      if (n < 4)
        for (int r = 0; r < 4; ++r)
          out[((size_t)t * 64 + (brow + r)) * 1024 + jj] = hv[r];
    }
    if (t == 1023 && n < 4)
      for (int r = 0; r < 4; ++r) outT[(size_t)(brow + r) * 1024 + jj] = hv[r];
  }
  if (n < 4) {
    for (int r = 0; r < 4; ++r) cst[(size_t)(brow + r) * 1024 + jj] = creg[r];
    if (t0 + C == 1024)
      for (int r = 0; r < 4; ++r) cT[(size_t)(brow + r) * 1024 + jj] = creg[r];
  }
}

// ---------------------------------------------------------------------------
extern "C" void kernel_launch(void* const* d_in, const int* in_sizes, int n_in,
                              void* d_out, int out_size, void* d_ws, size_t ws_size,
                              hipStream_t stream)
{
  const float* x    = (const float*)d_in[0];
  const float* W_ih = (const float*)d_in[1];
  const float* W_hh = (const float*)d_in[2];
  const float* b_ih = (const float*)d_in[3];
  const float* b_hh = (const float*)d_in[4];
  const float* h0   = (const float*)d_in[5];
  const float* c0   = (const float*)d_in[6];
  float* out  = (float*)d_out;
  float* outT = out + (size_t)1024 * 64 * 1024;   // h_T
  float* cT   = outT + 64 * 1024;                 // c_T

  unsigned char* ws = (unsigned char*)d_ws;
  size_t off = 0;
  u16* Wc = (u16*)(ws + off);      off += (size_t)4096 * 2048 * 2;  // 16 MiB
  float* bias = (float*)(ws + off); off += 4096 * 4;
  u16* hbuf = (u16*)(ws + off);    off += (size_t)2 * 65536 * 2;    // ping-pong h (bf16)
  float* cst = (float*)(ws + off); off += (size_t)65536 * 4;        // c state
  unsigned* arv = (unsigned*)(ws + off); off += 256 * 32 * 4;       // arrive flags, 128B padded
  u16* Xp = (u16*)(ws + off);      // 32 MiB chunk buffer; total ws need ~48.6 MiB

  hipMemsetAsync(arv, 0, 256 * 32 * 4, stream);
  hipLaunchKernelGGL(prep_kernel, dim3(4096), dim3(256), 0, stream,
                     W_ih, W_hh, b_ih, b_hh, h0, c0, Wc, bias, hbuf, cst);

  for (int c = 0; c < NCHUNK; ++c) {
    int t0 = c * CHUNK;
    hipLaunchKernelGGL(xproj_kernel, dim3(1024), dim3(256), 0, stream,
                       x + (size_t)t0 * 65536, Wc, Xp);
    int C = CHUNK;
    void* args[] = {&Wc, &Xp, &hbuf, &cst, &bias, &out, &outT, &cT, &arv, &t0, &C};
    if (hipLaunchCooperativeKernel(reinterpret_cast<void*>(scan_kernel),
                                   dim3(NWG), dim3(256), args, 0, stream) != hipSuccess) {
      (void)hipGetLastError();
      hipLaunchKernelGGL(scan_kernel, dim3(NWG), dim3(256), 0, stream,
                         Wc, Xp, hbuf, cst, bias, out, outT, cT, arv, t0, CHUNK);
    }
  }
}

// Round 4
// 14820.758 us; speedup vs baseline: 1.6428x; 1.1043x over previous
//
#include <hip/hip_runtime.h>

typedef unsigned short u16;
typedef __attribute__((ext_vector_type(8))) __bf16 bf16x8;
typedef __attribute__((ext_vector_type(4))) float f32x4;

// Problem constants
#define NWG 256
#define CHUNK 64          // timesteps per chunk (Xp chunk = 32 MiB bf16)
#define NCHUNK 16

__device__ __forceinline__ u16 f2b(float f) {
  union { float f; unsigned u; } v; v.f = f;
  unsigned r = (v.u + 0x7fffu + ((v.u >> 16) & 1u)) >> 16;
  return (u16)r;
}
__device__ __forceinline__ float b2f(u16 u) {
  union { unsigned u; float f; } v; v.u = ((unsigned)u) << 16;
  return v.f;
}
__device__ __forceinline__ float sig(float x) { return 1.0f / (1.0f + __expf(-x)); }
__device__ __forceinline__ float tanh_(float x) { return 2.0f / (1.0f + __expf(-2.0f * x)) - 1.0f; }

// ---------------------------------------------------------------------------
// prep: Wc[4096][2048] bf16 = [W_ih | W_hh]; bias = b_ih + b_hh (fp32);
//       hbuf parity-0 = bf16(h0); cst = c0 (fp32)
// ---------------------------------------------------------------------------
__global__ __launch_bounds__(256) void prep_kernel(
    const float* __restrict__ W_ih, const float* __restrict__ W_hh,
    const float* __restrict__ b_ih, const float* __restrict__ b_hh,
    const float* __restrict__ h0, const float* __restrict__ c0,
    u16* __restrict__ Wc, float* __restrict__ bias,
    u16* __restrict__ hbuf, float* __restrict__ cst)
{
  const int tid = threadIdx.x;
  const int blk = blockIdx.x;
  // weight row blk
  {
    const float4 a = *reinterpret_cast<const float4*>(W_ih + (size_t)blk * 1024 + tid * 4);
    const float4 b = *reinterpret_cast<const float4*>(W_hh + (size_t)blk * 1024 + tid * 4);
    u16* dst = Wc + (size_t)blk * 2048;
    *reinterpret_cast<ushort4*>(dst + tid * 4) =
        make_ushort4(f2b(a.x), f2b(a.y), f2b(a.z), f2b(a.w));
    *reinterpret_cast<ushort4*>(dst + 1024 + tid * 4) =
        make_ushort4(f2b(b.x), f2b(b.y), f2b(b.z), f2b(b.w));
  }
  if (blk < 16) {
    int i = blk * 256 + tid;
    bias[i] = b_ih[i] + b_hh[i];
  } else if (blk < 80) {
    int row = blk - 16, k = tid * 4;
    float4 v = *reinterpret_cast<const float4*>(h0 + (size_t)row * 1024 + k);
    *reinterpret_cast<ushort4*>(hbuf + (size_t)row * 1024 + k) =
        make_ushort4(f2b(v.x), f2b(v.y), f2b(v.z), f2b(v.w));
  } else if (blk < 144) {
    int row = blk - 80, k = tid * 4;
    *reinterpret_cast<float4*>(cst + (size_t)row * 1024 + k) =
        *reinterpret_cast<const float4*>(c0 + (size_t)row * 1024 + k);
  }
}

// ---------------------------------------------------------------------------
// xproj: gates for the chunk. Output layout is MFMA-fragment order for scan:
//   Xp[ts][gam][q][g][jr][b16]  (ts<64, gam<4 gate, q<64 16-col block,
//                               g<4 batch group, jr<16 col-in-block, b16<16 row)
// element (ts, gam, q, g, jr, b16) = gate preact of batch row 16g+b16,
// gate col gam*1024 + q*16 + jr, timestep t0+ts.
// 128x128 tile, 4 waves 2x2, K staged in 64-chunks, bf16 MFMA 16x16x32.
// ---------------------------------------------------------------------------
__global__ __launch_bounds__(256) void xproj_kernel(
    const float* __restrict__ xc, const u16* __restrict__ Wc, u16* __restrict__ Xp)
{
  __shared__ __align__(16) u16 As[128][72];   // pitch 72 -> 2-way (free) bank aliasing
  __shared__ __align__(16) u16 Bs[128][72];
  const int tid = threadIdx.x;
  const int w = tid >> 6, l = tid & 63;
  const int bm = blockIdx.x & 31;        // 32 m-tiles (M=4096)
  const int bn = blockIdx.x >> 5;        // 32 n-tiles (N=4096)
  const int m0 = bm << 7, n0 = bn << 7;
  const int wm = w & 1, wn = w >> 1;
  const int lr = l & 15, lq = l >> 4;

  f32x4 acc[4][4];
  for (int i = 0; i < 4; ++i)
    for (int j = 0; j < 4; ++j) acc[i][j] = (f32x4){0.f, 0.f, 0.f, 0.f};

  for (int kc = 0; kc < 1024; kc += 64) {
    {  // stage A (fp32 -> bf16): 128 rows x 64 k
      const int k4 = (tid & 15) << 2;
      const int rb = tid >> 4;
      for (int rp = 0; rp < 128; rp += 16) {
        int row = rp + rb;
        float4 v = *reinterpret_cast<const float4*>(xc + (size_t)(m0 + row) * 1024 + kc + k4);
        unsigned lo = (unsigned)f2b(v.x) | ((unsigned)f2b(v.y) << 16);
        unsigned hi = (unsigned)f2b(v.z) | ((unsigned)f2b(v.w) << 16);
        *reinterpret_cast<uint2*>(&As[row][k4]) = make_uint2(lo, hi);
      }
    }
    {  // stage B (already bf16): 128 rows x 64 k
      const int kk = (tid & 7) << 3;
      const int rb = tid >> 3;
      for (int rp = 0; rp < 128; rp += 32) {
        int row = rp + rb;
        uint4 v = *reinterpret_cast<const uint4*>(Wc + (size_t)(n0 + row) * 2048 + kc + kk);
        *reinterpret_cast<uint4*>(&Bs[row][kk]) = v;
      }
    }
    __syncthreads();
    for (int kb = 0; kb < 2; ++kb) {
      const int ko = kb * 32 + lq * 8;
      bf16x8 af[4], bfr[4];
      for (int i = 0; i < 4; ++i)
        af[i] = *reinterpret_cast<const bf16x8*>(&As[(wm << 6) + (i << 4) + lr][ko]);
      for (int j = 0; j < 4; ++j)
        bfr[j] = *reinterpret_cast<const bf16x8*>(&Bs[(wn << 6) + (j << 4) + lr][ko]);
      for (int i = 0; i < 4; ++i)
        for (int j = 0; j < 4; ++j)
          acc[i][j] = __builtin_amdgcn_mfma_f32_16x16x32_bf16(af[i], bfr[j], acc[i][j], 0, 0, 0);
    }
    __syncthreads();
  }
  // epilogue -> fragment-order layout. D row=(lane>>4)*4+r, col=lane&15.
  // m = m0 + wm*64 + i*16 + lq*4 + r  => ts = bm*2+wm, g = i, b16 = lq*4+r
  // n = n0 + wn*64 + j*16 + lr        => gam = bn>>3, q = (bn&7)*8+wn*4+j, jr = lr
  const int ts2 = (bm << 1) + wm;
  const int gam = bn >> 3;
  for (int i = 0; i < 4; ++i)
    for (int j = 0; j < 4; ++j) {
      const int q2 = ((bn & 7) << 3) + (wn << 2) + j;
      unsigned long long pk = (unsigned long long)f2b(acc[i][j][0])
                            | ((unsigned long long)f2b(acc[i][j][1]) << 16)
                            | ((unsigned long long)f2b(acc[i][j][2]) << 32)
                            | ((unsigned long long)f2b(acc[i][j][3]) << 48);
      size_t off = ((((size_t)(ts2 * 4 + gam) * 64 + q2) * 4 + i) * 16 + lr) * 16 + (lq << 2);
      *reinterpret_cast<unsigned long long*>(Xp + off) = pk;
    }
}

// ---------------------------------------------------------------------------
// scan: persistent, 256 WGs in 4 INDEPENDENT groups (batch-split).
// Group g owns batch rows [16g,16g+16); WG (g,q) owns h-cols [16q,16q+16).
// bid -> (g,q): g=(bid&7)>>1, q=((bid>>3)<<1)|(bid&1)  => group g's WGs live
// on XCD pair {2g,2g+1} under the canonical bid%8 mapping (locality only).
// Wave gam computes gate gam (16x16 tile, K=1024, W slice 128 KB in LDS).
// Gate combine via 4 KB LDS stage; elementwise = 256 threads = 16x16 cells.
// Grid barrier per step is over the 64 WGs of the group only.
// ---------------------------------------------------------------------------
__global__ __launch_bounds__(256, 1) void scan_kernel(
    const u16* __restrict__ Wc, const u16* __restrict__ Xp,
    u16* __restrict__ hbuf, float* __restrict__ cst, const float* __restrict__ bias,
    float* __restrict__ out, float* __restrict__ outT, float* __restrict__ cT,
    unsigned* __restrict__ arv, int t0, int C)
{
  __shared__ __align__(16) u16 Wlds[4 * 32 * 64 * 8];   // 128 KB: [gam][kb][lane][8]
  __shared__ __align__(16) float GsF[4 * 16 * 17];      // gate stage, padded
  __shared__ __align__(8) u16 Hs[256];                  // h tile bf16 [b16][j]
  const int tid = threadIdx.x;
  const int bid = blockIdx.x;
  const int g = (bid & 7) >> 1;                   // batch group 0..3
  const int q = ((bid >> 3) << 1) | (bid & 1);    // member in group 0..63
  const int w = tid >> 6, l = tid & 63;           // wave = gate
  const int g16 = g << 4, q16 = q << 4;
  const int member = (g << 6) + q;
  const int gBase = g << 6;

  // load W slice into LDS in B-fragment order:
  // Wlds[gam][kb][lane][8] <- Wc[gam*1024 + q*16 + (lane&15)][1024 + kb*32 + (lane>>4)*8 ..]
  for (int it = 0; it < 32; ++it) {
    int f = it * 256 + tid;
    int gf = f >> 11, rem = f & 2047;
    int kb = rem >> 6, lf = rem & 63;
    int colw = (gf << 10) + q16 + (lf & 15);
    int k0 = (kb << 5) + ((lf >> 4) << 3);
    uint4 v = *reinterpret_cast<const uint4*>(Wc + (size_t)colw * 2048 + 1024 + k0);
    *reinterpret_cast<uint4*>(&Wlds[f * 8]) = v;
  }
  const float biasv = bias[(w << 10) + q16 + (l & 15)];
  const int eb = tid >> 4, ej = tid & 15;         // elementwise cell (b16, j)
  float creg = cst[(size_t)(g16 + eb) * 1024 + q16 + ej];
  __syncthreads();

  // prefetch Xp fragment for ts=0: lane l reads (jr=l&15, b16=(l>>4)*4+r)
  float xv[4];
  {
    const u16* xp = Xp + (((size_t)(0 * 4 + w) * 64 + q) * 4 + g) * 256
                    + ((l & 15) << 4) + ((l >> 4) << 2);
    uint2 xr = *reinterpret_cast<const uint2*>(xp);
    xv[0] = b2f((u16)(xr.x & 0xffff)); xv[1] = b2f((u16)(xr.x >> 16));
    xv[2] = b2f((u16)(xr.y & 0xffff)); xv[3] = b2f((u16)(xr.y >> 16));
  }

  for (int ts = 0; ts < C; ++ts) {
    const int t = t0 + ts;
    const u16* hs = hbuf + ((t & 1) ? 65536 : 0);
    u16* hd = hbuf + ((t & 1) ? 0 : 65536);
    // A-fragment from global h rows [16g,16g+16): A[m=l&15][k=(l>>4)*8+..]
    const u16* arow = hs + (size_t)(g16 + (l & 15)) * 1024 + ((l >> 4) << 3);
    f32x4 ac0 = {0.f, 0.f, 0.f, 0.f};
    f32x4 ac1 = {0.f, 0.f, 0.f, 0.f};
#pragma unroll
    for (int kb = 0; kb < 32; kb += 2) {
      bf16x8 a0 = *reinterpret_cast<const bf16x8*>(arow + (kb << 5));
      bf16x8 a1 = *reinterpret_cast<const bf16x8*>(arow + ((kb + 1) << 5));
      ac0 = __builtin_amdgcn_mfma_f32_16x16x32_bf16(
          a0, *reinterpret_cast<const bf16x8*>(&Wlds[(((w << 5) + kb) * 64 + l) * 8]), ac0, 0, 0, 0);
      ac1 = __builtin_amdgcn_mfma_f32_16x16x32_bf16(
          a1, *reinterpret_cast<const bf16x8*>(&Wlds[(((w << 5) + kb + 1) * 64 + l) * 8]), ac1, 0, 0, 0);
    }
    // fold Xp + bias, stage to GsF[gam][b16][j] (pad 17)
#pragma unroll
    for (int r = 0; r < 4; ++r) {
      float val = (ac0[r] + ac1[r]) + xv[r] + biasv;
      GsF[((w << 4) + ((l >> 4) << 2) + r) * 17 + (l & 15)] = val;
    }
    __syncthreads();
    // elementwise: one (b16, j) cell per thread, no divergence
    float gi = sig(GsF[(0 * 16 + eb) * 17 + ej]);
    float gf_ = sig(GsF[(1 * 16 + eb) * 17 + ej]);
    float gg = tanh_(GsF[(2 * 16 + eb) * 17 + ej]);
    float go = sig(GsF[(3 * 16 + eb) * 17 + ej]);
    float cn = gf_ * creg + gi * gg;
    float hv = go * tanh_(cn);
    creg = cn;
    Hs[tid] = f2b(hv);
    // prefetch next step's Xp fragment (constant data, no ordering needed)
    if (ts + 1 < C) {
      const u16* xp = Xp + (((size_t)((ts + 1) * 4 + w) * 64 + q) * 4 + g) * 256
                      + ((l & 15) << 4) + ((l >> 4) << 2);
      uint2 xr = *reinterpret_cast<const uint2*>(xp);
      xv[0] = b2f((u16)(xr.x & 0xffff)); xv[1] = b2f((u16)(xr.x >> 16));
      xv[2] = b2f((u16)(xr.y & 0xffff)); xv[3] = b2f((u16)(xr.y >> 16));
    }
    __syncthreads();  // Hs complete

    if (ts + 1 < C) {
      const unsigned v = (unsigned)(t + 1);
      if (tid < 64) {
        // packed 8B write-through h store: row=tid>>2, 4 cols at (tid&3)*4
        unsigned long long st =
            *reinterpret_cast<const unsigned long long*>(&Hs[((tid >> 2) << 4) + ((tid & 3) << 2)]);
        __hip_atomic_store(
            reinterpret_cast<unsigned long long*>(
                hd + (size_t)(g16 + (tid >> 2)) * 1024 + q16 + ((tid & 3) << 2)),
            st, __ATOMIC_RELAXED, __HIP_MEMORY_SCOPE_AGENT);
        if (tid == 0) {
          asm volatile("s_waitcnt vmcnt(0)" ::: "memory");
          __hip_atomic_store(&arv[member << 5], v, __ATOMIC_RELAXED, __HIP_MEMORY_SCOPE_AGENT);
        }
      }
      // out store fully in the poll shadow (host-only data)
      __hip_atomic_store(&out[((size_t)t * 64 + g16 + eb) * 1024 + q16 + ej], hv,
                         __ATOMIC_RELAXED, __HIP_MEMORY_SCOPE_AGENT);
      // group-local barrier: thread tid<64 polls member tid of THIS group
      if (tid < 64)
        while (__hip_atomic_load(&arv[(gBase + tid) << 5], __ATOMIC_RELAXED,
                                 __HIP_MEMORY_SCOPE_AGENT) < v)
          __builtin_amdgcn_s_sleep(1);
      __syncthreads();
      __builtin_amdgcn_fence(__ATOMIC_ACQUIRE, "agent");  // inv L1/L2 before h loads
    } else {
      // last step of chunk: kernel boundary provides the sync
      if (tid < 64) {
        unsigned long long st =
            *reinterpret_cast<const unsigned long long*>(&Hs[((tid >> 2) << 4) + ((tid & 3) << 2)]);
        *reinterpret_cast<unsigned long long*>(
            hd + (size_t)(g16 + (tid >> 2)) * 1024 + q16 + ((tid & 3) << 2)) = st;
      }
      out[((size_t)t * 64 + g16 + eb) * 1024 + q16 + ej] = hv;
      if (t == 1023) outT[(size_t)(g16 + eb) * 1024 + q16 + ej] = hv;
    }
  }
  cst[(size_t)(g16 + eb) * 1024 + q16 + ej] = creg;
  if (t0 + C == 1024) cT[(size_t)(g16 + eb) * 1024 + q16 + ej] = creg;
}

// ---------------------------------------------------------------------------
extern "C" void kernel_launch(void* const* d_in, const int* in_sizes, int n_in,
                              void* d_out, int out_size, void* d_ws, size_t ws_size,
                              hipStream_t stream)
{
  const float* x    = (const float*)d_in[0];
  const float* W_ih = (const float*)d_in[1];
  const float* W_hh = (const float*)d_in[2];
  const float* b_ih = (const float*)d_in[3];
  const float* b_hh = (const float*)d_in[4];
  const float* h0   = (const float*)d_in[5];
  const float* c0   = (const float*)d_in[6];
  float* out  = (float*)d_out;
  float* outT = out + (size_t)1024 * 64 * 1024;   // h_T
  float* cT   = outT + 64 * 1024;                 // c_T

  unsigned char* ws = (unsigned char*)d_ws;
  size_t off = 0;
  u16* Wc = (u16*)(ws + off);      off += (size_t)4096 * 2048 * 2;  // 16 MiB
  float* bias = (float*)(ws + off); off += 4096 * 4;
  u16* hbuf = (u16*)(ws + off);    off += (size_t)2 * 65536 * 2;    // ping-pong h (bf16)
  float* cst = (float*)(ws + off); off += (size_t)65536 * 4;        // c state
  unsigned* arv = (unsigned*)(ws + off); off += 256 * 32 * 4;       // arrive flags, 128B padded
  u16* Xp = (u16*)(ws + off);      // 32 MiB chunk buffer; total ws need ~48.6 MiB

  hipMemsetAsync(arv, 0, 256 * 32 * 4, stream);
  hipLaunchKernelGGL(prep_kernel, dim3(4096), dim3(256), 0, stream,
                     W_ih, W_hh, b_ih, b_hh, h0, c0, Wc, bias, hbuf, cst);

  for (int c = 0; c < NCHUNK; ++c) {
    int t0 = c * CHUNK;
    hipLaunchKernelGGL(xproj_kernel, dim3(1024), dim3(256), 0, stream,
                       x + (size_t)t0 * 65536, Wc, Xp);
    int C = CHUNK;
    void* args[] = {&Wc, &Xp, &hbuf, &cst, &bias, &out, &outT, &cT, &arv, &t0, &C};
    if (hipLaunchCooperativeKernel(reinterpret_cast<void*>(scan_kernel),
                                   dim3(NWG), dim3(256), args, 0, stream) != hipSuccess) {
      (void)hipGetLastError();
      hipLaunchKernelGGL(scan_kernel, dim3(NWG), dim3(256), 0, stream,
                         Wc, Xp, hbuf, cst, bias, out, outT, cT, arv, t0, CHUNK);
    }
  }
}